// Round 2
// baseline (302.707 us; speedup 1.0000x reference)
//
#include <hip/hip_runtime.h>
#include <math.h>

#define BATCH 32768
#define LW    200
#define CIN   6
#define KSZ   5
#define FLAT  196     // LW - KSZ + 1
#define NH1   50
#define NH2   30
#define NOUT  15

// -------------------- Kernel 1: conv1d (valid) --------------------
// thread -> (batch, 4 consecutive outputs). 49 threads cover one batch row.
// i0 = 4q is 4-float aligned -> float4 loads/stores are 16B aligned.
__global__ __launch_bounds__(256) void conv_kernel(
    const float* __restrict__ x, const float* __restrict__ cw,
    const float* __restrict__ cb, float* __restrict__ co)
{
    int t = blockIdx.x * 256 + threadIdx.x;   // 0 .. BATCH*49-1 exactly
    int b = t / 49;
    int q = t - b * 49;
    int i0 = q * 4;

    // conv weights: uniform indices -> scalar loads
    float w[CIN][KSZ];
#pragma unroll
    for (int c = 0; c < CIN; ++c)
#pragma unroll
        for (int k = 0; k < KSZ; ++k) w[c][k] = cw[c * KSZ + k];
    float bias = cb[0];

    float acc0 = bias, acc1 = bias, acc2 = bias, acc3 = bias;
    const float* xb = x + (long)b * (CIN * LW) + i0;
#pragma unroll
    for (int c = 0; c < CIN; ++c) {
        float4 lo = *(const float4*)(xb + c * LW);
        float4 hi = *(const float4*)(xb + c * LW + 4);
        float xf[8] = {lo.x, lo.y, lo.z, lo.w, hi.x, hi.y, hi.z, hi.w};
#pragma unroll
        for (int k = 0; k < KSZ; ++k) {
            acc0 = fmaf(xf[k + 0], w[c][k], acc0);
            acc1 = fmaf(xf[k + 1], w[c][k], acc1);
            acc2 = fmaf(xf[k + 2], w[c][k], acc2);
            acc3 = fmaf(xf[k + 3], w[c][k], acc3);
        }
    }
    *(float4*)(co + (long)b * FLAT + i0) = make_float4(acc0, acc1, acc2, acc3);
}

// -------------------- Kernel 2: fc1+fc2+fc3 + Procrustes --------------------
// block = 256 threads = 4 waves; 64 batches per block (batch = lane).
// Wave wv accumulates fc1 partials over i in [49*wv, 49*wv+49); weight
// indices are wave-uniform -> s_load broadcast. Partials reduced via LDS,
// wave 0 finishes fc2/fc3 and the closest-proper-rotation (Davenport K
// matrix, double-precision Jacobi eigensolve — gap-independent accuracy).
__global__ __launch_bounds__(256) void mlp_kernel(
    const float* __restrict__ co,
    const float* __restrict__ w1, const float* __restrict__ b1,
    const float* __restrict__ w2, const float* __restrict__ b2,
    const float* __restrict__ w3, const float* __restrict__ b3,
    float* __restrict__ out)
{
    __shared__ float part[3][64][52];   // waves 1..3 partial h1, pad to 52

    int tid  = threadIdx.x;
    int wv   = __builtin_amdgcn_readfirstlane(tid >> 6);  // force SGPR (uniform)
    int lane = tid & 63;
    int b    = blockIdx.x * 64 + lane;
    int ibase = wv * 49;

    // per-lane load of this wave's 49 conv outputs (compiler merges to dwordx4)
    float cl[49];
    const float* crow = co + (long)b * FLAT + ibase;
#pragma unroll
    for (int ii = 0; ii < 49; ++ii) cl[ii] = crow[ii];

    float h1p[NH1];
#pragma unroll
    for (int j = 0; j < NH1; ++j) h1p[j] = 0.f;

#pragma unroll
    for (int ii = 0; ii < 49; ++ii) {
        float c = cl[ii];
        const float* row = w1 + (ibase + ii) * NH1;   // uniform -> s_load
#pragma unroll
        for (int j = 0; j < NH1; ++j) h1p[j] = fmaf(c, row[j], h1p[j]);
    }

    if (wv != 0) {
#pragma unroll
        for (int j = 0; j < NH1; ++j) part[wv - 1][lane][j] = h1p[j];
    }
    __syncthreads();
    if (wv != 0) return;

    // reduce + bias + relu
    float h1[NH1];
#pragma unroll
    for (int j = 0; j < NH1; ++j) {
        float s = h1p[j] + part[0][lane][j] + part[1][lane][j] + part[2][lane][j] + b1[j];
        h1[j] = fmaxf(s, 0.f);
    }

    // fc2
    float h2[NH2];
#pragma unroll
    for (int j = 0; j < NH2; ++j) h2[j] = b2[j];
#pragma unroll
    for (int k = 0; k < NH1; ++k) {
        float hk = h1[k];
        const float* row = w2 + k * NH2;              // uniform -> s_load
#pragma unroll
        for (int j = 0; j < NH2; ++j) h2[j] = fmaf(hk, row[j], h2[j]);
    }
#pragma unroll
    for (int j = 0; j < NH2; ++j) h2[j] = fmaxf(h2[j], 0.f);

    // fc3 (no relu)
    float o[NOUT];
#pragma unroll
    for (int j = 0; j < NOUT; ++j) o[j] = b3[j];
#pragma unroll
    for (int k = 0; k < NH2; ++k) {
        float hk = h2[k];
        const float* row = w3 + k * NOUT;             // uniform -> s_load
#pragma unroll
        for (int j = 0; j < NOUT; ++j) o[j] = fmaf(hk, row[j], o[j]);
    }

    // ---- closest proper rotation to R = o[0..8] (row-major) ----
    // Maximize tr(Q^T R) = q^T K q over unit quaternions (Davenport/Horn).
    // Top eigenvector of K == U diag(1,1,det(UV^T)) V^T of the reference SVD
    // path. Solved with full Jacobi eigendecomposition in double: accuracy is
    // independent of the eigenvalue gap (power iteration failed here on
    // near-degenerate sigma2 ~= sigma3, det<0 batches).
    {
        double r00 = (double)o[0], r01 = (double)o[1], r02 = (double)o[2];
        double r10 = (double)o[3], r11 = (double)o[4], r12 = (double)o[5];
        double r20 = (double)o[6], r21 = (double)o[7], r22 = (double)o[8];

        double A[4][4], V[4][4];
        A[0][0] = r00 + r11 + r22;
        A[1][1] = r00 - r11 - r22;
        A[2][2] = r11 - r00 - r22;
        A[3][3] = r22 - r00 - r11;
        A[0][1] = A[1][0] = r21 - r12;
        A[0][2] = A[2][0] = r02 - r20;
        A[0][3] = A[3][0] = r10 - r01;
        A[1][2] = A[2][1] = r01 + r10;
        A[1][3] = A[3][1] = r02 + r20;
        A[2][3] = A[3][2] = r12 + r21;
#pragma unroll
        for (int i = 0; i < 4; ++i)
#pragma unroll
            for (int j = 0; j < 4; ++j) V[i][j] = (i == j) ? 1.0 : 0.0;

        const int pr[6][2] = {{0,1},{0,2},{0,3},{1,2},{1,3},{2,3}};
        for (int sweep = 0; sweep < 6; ++sweep) {
#pragma unroll
            for (int pi = 0; pi < 6; ++pi) {
                const int p = pr[pi][0], q = pr[pi][1];
                double apq = A[p][q];
                if (apq != 0.0) {
                    double theta = (A[q][q] - A[p][p]) / (2.0 * apq);
                    double t = copysign(1.0, theta) / (fabs(theta) + sqrt(1.0 + theta * theta));
                    double c = 1.0 / sqrt(1.0 + t * t);
                    double s = t * c;
                    // A := R^T A R  (R: rot in (p,q) plane, R[p][p]=c, R[p][q]=s, R[q][p]=-s, R[q][q]=c)
#pragma unroll
                    for (int k = 0; k < 4; ++k) {           // columns
                        double akp = A[k][p], akq = A[k][q];
                        A[k][p] = c * akp - s * akq;
                        A[k][q] = s * akp + c * akq;
                    }
#pragma unroll
                    for (int k = 0; k < 4; ++k) {           // rows
                        double apk = A[p][k], aqk = A[q][k];
                        A[p][k] = c * apk - s * aqk;
                        A[q][k] = s * apk + c * aqk;
                    }
#pragma unroll
                    for (int k = 0; k < 4; ++k) {           // eigenvectors
                        double vkp = V[k][p], vkq = V[k][q];
                        V[k][p] = c * vkp - s * vkq;
                        V[k][q] = s * vkp + c * vkq;
                    }
                }
            }
        }

        int best = 0;
        double bl = A[0][0];
#pragma unroll
        for (int i = 1; i < 4; ++i) {
            if (A[i][i] > bl) { bl = A[i][i]; best = i; }
        }
        double vw = V[0][best], vx = V[1][best], vy = V[2][best], vz = V[3][best];
        double inv = 1.0 / sqrt(vw * vw + vx * vx + vy * vy + vz * vz);
        vw *= inv; vx *= inv; vy *= inv; vz *= inv;

        double xx = vx * vx, yy = vy * vy, zz = vz * vz;
        double xy = vx * vy, xz = vx * vz, yz = vy * vz;
        double wx = vw * vx, wy = vw * vy, wz = vw * vz;

        float* ob = out + (long)b * NOUT;
        ob[0]  = (float)(1.0 - 2.0 * (yy + zz));
        ob[1]  = (float)(2.0 * (xy - wz));
        ob[2]  = (float)(2.0 * (xz + wy));
        ob[3]  = (float)(2.0 * (xy + wz));
        ob[4]  = (float)(1.0 - 2.0 * (xx + zz));
        ob[5]  = (float)(2.0 * (yz - wx));
        ob[6]  = (float)(2.0 * (xz - wy));
        ob[7]  = (float)(2.0 * (yz + wx));
        ob[8]  = (float)(1.0 - 2.0 * (xx + yy));
        ob[9]  = o[9];
        ob[10] = o[10];
        ob[11] = o[11];
        ob[12] = o[12];
        ob[13] = o[13];
        ob[14] = o[14];
    }
}

extern "C" void kernel_launch(void* const* d_in, const int* in_sizes, int n_in,
                              void* d_out, int out_size, void* d_ws, size_t ws_size,
                              hipStream_t stream) {
    const float* x  = (const float*)d_in[0];
    const float* cw = (const float*)d_in[1];
    const float* cb = (const float*)d_in[2];
    const float* w1 = (const float*)d_in[3];
    const float* b1 = (const float*)d_in[4];
    const float* w2 = (const float*)d_in[5];
    const float* b2 = (const float*)d_in[6];
    const float* w3 = (const float*)d_in[7];
    const float* b3 = (const float*)d_in[8];
    float* outp = (float*)d_out;
    float* co   = (float*)d_ws;   // BATCH*FLAT floats = 25.7 MB scratch

    conv_kernel<<<(BATCH * 49) / 256, 256, 0, stream>>>(x, cw, cb, co);
    mlp_kernel<<<BATCH / 64, 256, 0, stream>>>(co, w1, b1, w2, b2, w3, b3, outp);
}